// Round 1
// baseline (1939.645 us; speedup 1.0000x reference)
//
#include <hip/hip_runtime.h>

#define DEV __device__ __forceinline__

typedef __attribute__((ext_vector_type(8))) short bf16x8;
typedef __attribute__((ext_vector_type(4))) float f32x4;
typedef unsigned short u16;
typedef __attribute__((address_space(1))) const void* gvp;
typedef __attribute__((address_space(3))) void* svp;

DEV u16 f2bf(float f){
  unsigned u = __float_as_uint(f);
  u = (u + 0x7FFFu + ((u >> 16) & 1u)) >> 16;
  return (u16)u;
}
DEV float bf2f(u16 v){ return __uint_as_float(((unsigned)v) << 16); }

// ---------------- convert f32 -> bf16 ----------------
__global__ void k_cvt(const float* __restrict__ s, u16* __restrict__ d, int n){
  int i = blockIdx.x * 256 + threadIdx.x;
  if (i < n) d[i] = f2bf(s[i]);
}

// ---------------- layernorm over D=1024, bf16 out ----------------
__global__ __launch_bounds__(256) void k_ln(const float* __restrict__ x, const float* __restrict__ w,
                                            const float* __restrict__ b, u16* __restrict__ y){
  const int row = blockIdx.x;
  const int tid = threadIdx.x;
  const float4 v = ((const float4*)(x + (size_t)row * 1024))[tid];
  float s1 = v.x + v.y + v.z + v.w;
  float s2 = v.x*v.x + v.y*v.y + v.z*v.z + v.w*v.w;
  #pragma unroll
  for (int o = 32; o > 0; o >>= 1){ s1 += __shfl_down(s1, o); s2 += __shfl_down(s2, o); }
  __shared__ float r1[4], r2[4];
  __shared__ float mu_s, rs_s;
  const int wv = tid >> 6;
  if ((tid & 63) == 0){ r1[wv] = s1; r2[wv] = s2; }
  __syncthreads();
  if (tid == 0){
    float t1 = r1[0]+r1[1]+r1[2]+r1[3], t2 = r2[0]+r2[1]+r2[2]+r2[3];
    float mu = t1 * (1.0f/1024.0f);
    float var = t2 * (1.0f/1024.0f) - mu*mu;
    mu_s = mu; rs_s = rsqrtf(var + 1e-6f);
  }
  __syncthreads();
  const float mu = mu_s, rs = rs_s;
  const float4 wv4 = ((const float4*)w)[tid];
  const float4 bv4 = ((const float4*)b)[tid];
  ushort4 o4;
  o4.x = f2bf((v.x-mu)*rs*wv4.x + bv4.x);
  o4.y = f2bf((v.y-mu)*rs*wv4.y + bv4.y);
  o4.z = f2bf((v.z-mu)*rs*wv4.z + bv4.z);
  o4.w = f2bf((v.w-mu)*rs*wv4.w + bv4.w);
  ((ushort4*)(y + (size_t)row*1024))[tid] = o4;
}

// ---------------- bf16 MFMA GEMM: C = A(MxK) * Bw(NxK)^T + bias ----------------
// MODE 0: bf16 store. MODE 1: gelu(tanh approx) then bf16 store. MODE 2: f32 out[off] += v
template<int MODE>
__launch_bounds__(256)
__global__ void k_gemm(const u16* __restrict__ A, const u16* __restrict__ Bw,
                       const float* __restrict__ bias, void* __restrict__ out,
                       int M, int N, int K)
{
  __shared__ __align__(16) u16 As[8192];   // [128 rows][64 k] bf16, XOR-swizzled contents
  __shared__ __align__(16) u16 Bs[8192];
  const int tid = threadIdx.x;
  const int wave = tid >> 6;
  const int lane = tid & 63;
  const int l15 = lane & 15, l4 = lane >> 4;
  const int wr = wave >> 1, wc = wave & 1;
  const int bn = blockIdx.x, bm = blockIdx.y;
  const size_t ar0 = (size_t)bm * 128;
  const size_t br0 = (size_t)bn * 128;

  f32x4 acc[4][4];
  const f32x4 z4 = {0.f, 0.f, 0.f, 0.f};
  #pragma unroll
  for (int m = 0; m < 4; ++m)
    #pragma unroll
    for (int n = 0; n < 4; ++n) acc[m][n] = z4;

  for (int k0 = 0; k0 < K; k0 += 64){
    #pragma unroll
    for (int i = 0; i < 4; ++i){
      const int id = i*256 + tid;
      const int row = id >> 3, ch = id & 7;
      const int chs = ch ^ (row & 7);            // inverse-swizzled source chunk
      const u16* ga = A  + (ar0 + row) * (size_t)K + k0 + chs*8;
      const u16* gb = Bw + (br0 + row) * (size_t)K + k0 + chs*8;
      u16* la = As + (size_t)(i*256 + wave*64) * 8;  // wave-uniform base; HW adds lane*16B
      u16* lb = Bs + (size_t)(i*256 + wave*64) * 8;
      __builtin_amdgcn_global_load_lds((gvp)ga, (svp)la, 16, 0, 0);
      __builtin_amdgcn_global_load_lds((gvp)gb, (svp)lb, 16, 0, 0);
    }
    __syncthreads();
    #pragma unroll
    for (int kk = 0; kk < 64; kk += 32){
      bf16x8 af[4], bfrag[4];
      #pragma unroll
      for (int m = 0; m < 4; ++m){
        const int r = wr*64 + m*16 + l15;
        const int c = (kk + l4*8) ^ ((r & 7) * 8);   // swizzled read
        af[m] = *(const bf16x8*)(As + r*64 + c);
      }
      #pragma unroll
      for (int n = 0; n < 4; ++n){
        const int r = wc*64 + n*16 + l15;
        const int c = (kk + l4*8) ^ ((r & 7) * 8);
        bfrag[n] = *(const bf16x8*)(Bs + r*64 + c);
      }
      #pragma unroll
      for (int m = 0; m < 4; ++m)
        #pragma unroll
        for (int n = 0; n < 4; ++n)
          acc[m][n] = __builtin_amdgcn_mfma_f32_16x16x32_bf16(af[m], bfrag[n], acc[m][n], 0, 0, 0);
    }
    __syncthreads();
  }

  #pragma unroll
  for (int m = 0; m < 4; ++m){
    const int gr0 = bm*128 + wr*64 + m*16 + l4*4;
    #pragma unroll
    for (int n = 0; n < 4; ++n){
      const int gc = bn*128 + wc*64 + n*16 + l15;
      const float bv = bias[gc];
      #pragma unroll
      for (int r2 = 0; r2 < 4; ++r2){
        const size_t off = (size_t)(gr0 + r2) * N + gc;
        float v = acc[m][n][r2] + bv;
        if (MODE == 0){
          ((u16*)out)[off] = f2bf(v);
        } else if (MODE == 1){
          const float a = 0.7978845608028654f * (v + 0.044715f * v * v * v);
          const float e = __expf(2.0f * a);
          const float th = (e - 1.0f) / (e + 1.0f);
          ((u16*)out)[off] = f2bf(0.5f * v * (1.0f + th));
        } else {
          float* op = (float*)out;
          op[off] += v;
        }
      }
    }
  }
}

// ---------------- transpose (B,L,H,64) -> (B,H,64,L) per (b,h), bf16 ----------------
__global__ __launch_bounds__(256) void k_tr(const u16* __restrict__ Q, u16* __restrict__ Qt){
  __shared__ u16 Ls[64][65];
  const int tid = threadIdx.x;
  const int bh = blockIdx.y;
  const int b = bh >> 4, h = bh & 15;
  const int l0 = blockIdx.x * 64;
  #pragma unroll
  for (int i = 0; i < 16; ++i){
    const int id = i*256 + tid;
    const int lr = id >> 6, dc = id & 63;
    Ls[lr][dc] = Q[((size_t)b*4096 + l0 + lr)*1024 + h*64 + dc];
  }
  __syncthreads();
  #pragma unroll
  for (int i = 0; i < 16; ++i){
    const int id = i*256 + tid;
    const int dr = id >> 6, lc = id & 63;
    Qt[((size_t)bh*64 + dr)*4096 + l0 + lc] = Ls[lc][dr];
  }
}

// ---------------- in-LDS radix-2 DIT FFT, N=4096, 256 threads ----------------
DEV void fft4096(float2* Z, const float2* tw, int tid, bool inv){
  for (int i = tid; i < 4096; i += 256){
    const int j = (int)(__brev((unsigned)i) >> 20);
    if (i < j){ float2 t = Z[i]; Z[i] = Z[j]; Z[j] = t; }
  }
  __syncthreads();
  for (int s = 1; s <= 12; ++s){
    const int half = 1 << (s - 1);
    for (int t = tid; t < 2048; t += 256){
      const int j = t & (half - 1);
      const int i0 = ((t >> (s-1)) << s) + j;
      const int i1 = i0 + half;
      float2 w = tw[j << (12 - s)];
      const float wy = inv ? -w.y : w.y;
      const float2 u = Z[i0], v = Z[i1];
      const float vr = v.x * w.x - v.y * wy;
      const float vi = v.x * wy + v.y * w.x;
      Z[i0] = make_float2(u.x + vr, u.y + vi);
      Z[i1] = make_float2(u.x - vr, u.y - vi);
    }
    __syncthreads();
  }
}

// ---------------- FFT of (q + i*k) per (b,h,d); accumulate S[f] = sum_d qf*conj(kf) ----------------
__global__ __launch_bounds__(256) void k_fftcorr(const u16* __restrict__ Qt, const u16* __restrict__ Kt,
                                                 float* __restrict__ S){
  __shared__ float2 Z[4096];      // 32 KB
  __shared__ float2 tw[2048];     // 16 KB
  const int tid = threadIdx.x;
  const int bh = blockIdx.x, dg = blockIdx.y;
  for (int k = tid; k < 2048; k += 256){
    float sn, cs;
    sincosf(-1.5339807878856412e-03f * (float)k, &sn, &cs);   // -2*pi/4096 * k
    tw[k] = make_float2(cs, sn);
  }
  float2 sa[16];
  #pragma unroll
  for (int j = 0; j < 16; ++j) sa[j] = make_float2(0.f, 0.f);
  __syncthreads();
  for (int dd = 0; dd < 16; ++dd){
    const int d = dg*16 + dd;
    const u16* q  = Qt + ((size_t)bh*64 + d) * 4096;
    const u16* kp = Kt + ((size_t)bh*64 + d) * 4096;
    for (int i = tid; i < 4096; i += 256)
      Z[i] = make_float2(bf2f(q[i]), bf2f(kp[i]));
    __syncthreads();
    fft4096(Z, tw, tid, false);
    #pragma unroll
    for (int j = 0; j < 16; ++j){
      const int f = j*256 + tid;
      const float2 a = Z[f];
      const float2 c = Z[(4096 - f) & 4095];
      const float qr = 0.5f * (a.x + c.x);
      const float qi = 0.5f * (a.y - c.y);
      const float kr = 0.5f * (a.y + c.y);
      const float ki = 0.5f * (c.x - a.x);
      sa[j].x += qr*kr + qi*ki;     // Re(qf * conj(kf))
      sa[j].y += qi*kr - qr*ki;     // Im(qf * conj(kf))
    }
    __syncthreads();
  }
  float* Sg = S + (size_t)bh * 8192;
  #pragma unroll
  for (int j = 0; j < 16; ++j){
    const int f = j*256 + tid;
    atomicAdd(&Sg[2*f + 0], sa[j].x);
    atomicAdd(&Sg[2*f + 1], sa[j].y);
  }
}

// ---------------- inverse FFT of S -> corr; softmax over L -> attn ----------------
__global__ __launch_bounds__(256) void k_isoftmax(const float* __restrict__ S, float* __restrict__ attn){
  __shared__ float2 Z[4096];
  __shared__ float2 tw[2048];
  __shared__ float red[4];
  __shared__ float bc;
  const int tid = threadIdx.x;
  const int bh = blockIdx.x;
  for (int k = tid; k < 2048; k += 256){
    float sn, cs;
    sincosf(-1.5339807878856412e-03f * (float)k, &sn, &cs);
    tw[k] = make_float2(cs, sn);
  }
  const float2* Sg = (const float2*)(S + (size_t)bh * 8192);
  for (int i = tid; i < 4096; i += 256) Z[i] = Sg[i];
  __syncthreads();
  fft4096(Z, tw, tid, true);          // unnormalized inverse
  const float scale = 1.0f / (4096.0f * 64.0f);   // 1/N (ifft) * 1/HD (mean over d)
  float cr[16];
  float lmax = -1e30f;
  #pragma unroll
  for (int j = 0; j < 16; ++j){
    const float c = Z[j*256 + tid].x * scale;
    cr[j] = c;
    lmax = fmaxf(lmax, c);
  }
  #pragma unroll
  for (int o = 32; o > 0; o >>= 1) lmax = fmaxf(lmax, __shfl_down(lmax, o));
  if ((tid & 63) == 0) red[tid >> 6] = lmax;
  __syncthreads();
  if (tid == 0) bc = fmaxf(fmaxf(red[0], red[1]), fmaxf(red[2], red[3]));
  __syncthreads();
  const float gmax = bc;
  float lsum = 0.f;
  #pragma unroll
  for (int j = 0; j < 16; ++j){ cr[j] = __expf(cr[j] - gmax); lsum += cr[j]; }
  #pragma unroll
  for (int o = 32; o > 0; o >>= 1) lsum += __shfl_down(lsum, o);
  if ((tid & 63) == 0) red[tid >> 6] = lsum;
  __syncthreads();
  if (tid == 0) bc = red[0] + red[1] + red[2] + red[3];
  __syncthreads();
  const float inv = 1.0f / bc;
  float* at = attn + (size_t)bh * 4096;
  #pragma unroll
  for (int j = 0; j < 16; ++j) at[j*256 + tid] = cr[j] * inv;
}

// ---------------- out[b,h,d] = sum_l attn[b,h,l] * V[b,l,h,d]; store lossy-transposed ----------------
__global__ __launch_bounds__(256) void k_av(const float* __restrict__ attn, const u16* __restrict__ V,
                                            float* __restrict__ oav){
  const int bh = blockIdx.x;
  const int b = bh >> 4, h = bh & 15;
  const int tid = threadIdx.x;
  const int d = tid & 63, lg = tid >> 6;
  const u16* vb = V + (size_t)b*4096*1024 + h*64 + d;
  const float* at = attn + (size_t)bh * 4096;
  float acc = 0.f;
  for (int l = lg*1024; l < lg*1024 + 1024; ++l)
    acc += at[l] * bf2f(vb[(size_t)l * 1024]);
  __shared__ float part[4][64];
  part[lg][d] = acc;
  __syncthreads();
  if (lg == 0)
    oav[(size_t)b*1024 + d*16 + h] = part[0][d] + part[1][d] + part[2][d] + part[3][d];  // flat idx = hd*H + h
}

// ---------------- proj = oav @ Wo^T + bo  (8 x 1024) ----------------
__global__ __launch_bounds__(256) void k_proj(const float* __restrict__ oav, const float* __restrict__ Wo,
                                              const float* __restrict__ bo, float* __restrict__ proj){
  const int b = blockIdx.x;
  const int o = blockIdx.y * 256 + threadIdx.x;
  __shared__ float xin[1024];
  for (int i = threadIdx.x; i < 1024; i += 256) xin[i] = oav[(size_t)b*1024 + i];
  __syncthreads();
  float acc = bo[o];
  const float4* wr = (const float4*)(Wo + (size_t)o * 1024);
  #pragma unroll 4
  for (int i = 0; i < 256; ++i){
    const float4 w4 = wr[i];
    acc += xin[4*i]*w4.x + xin[4*i+1]*w4.y + xin[4*i+2]*w4.z + xin[4*i+3]*w4.w;
  }
  proj[(size_t)b*1024 + o] = acc;
}

// ---------------- x1 = x + proj; x2 = x1 - movavg25(x1, zero-padded); write x2 to out ----------------
__global__ __launch_bounds__(256) void k_decomp(const float* __restrict__ x, const float* __restrict__ proj,
                                                float* __restrict__ out){
  const int row = blockIdx.x;           // b*4096 + l
  const int b = row >> 12, l = row & 4095;
  const int d = blockIdx.y * 256 + threadIdx.x;
  const float pv = proj[(size_t)b*1024 + d];
  const float* xb = x + (size_t)b * 4096 * 1024 + d;
  float wsum = 0.f; float cnt;
  if (l >= 12 && l < 4084){
    #pragma unroll
    for (int j = -12; j <= 12; ++j) wsum += xb[(size_t)(l + j) * 1024];
    cnt = 25.f;
  } else {
    cnt = 0.f;
    #pragma unroll
    for (int j = -12; j <= 12; ++j){
      const int ll = l + j;
      if (0 <= ll && ll < 4096){ wsum += xb[(size_t)ll * 1024]; cnt += 1.f; }
    }
  }
  const float xc = xb[(size_t)l * 1024];
  out[(size_t)row * 1024 + d] = xc + pv - (wsum + cnt * pv) * 0.04f;
}

extern "C" void kernel_launch(void* const* d_in, const int* in_sizes, int n_in,
                              void* d_out, int out_size, void* d_ws, size_t ws_size,
                              hipStream_t stream){
  const float* x    = (const float*)d_in[0];
  const float* ln1w = (const float*)d_in[1];
  const float* ln1b = (const float*)d_in[2];
  const float* Wq   = (const float*)d_in[3];
  const float* bq   = (const float*)d_in[4];
  const float* Wk   = (const float*)d_in[5];
  const float* bk   = (const float*)d_in[6];
  const float* Wv   = (const float*)d_in[7];
  const float* bv   = (const float*)d_in[8];
  const float* Wo   = (const float*)d_in[9];
  const float* bo   = (const float*)d_in[10];
  const float* ln2w = (const float*)d_in[11];
  const float* ln2b = (const float*)d_in[12];
  const float* W1   = (const float*)d_in[13];
  const float* b1   = (const float*)d_in[14];
  const float* W2   = (const float*)d_in[15];
  const float* b2   = (const float*)d_in[16];
  float* out = (float*)d_out;

  char* ws = (char*)d_ws;
  // Region A [0, 256MB): Q, K, V, Qt early; H1 (32768x4096 bf16) late.
  u16* Q    = (u16*)(ws + 0);
  u16* Kb   = (u16*)(ws + 67108864);
  u16* V    = (u16*)(ws + 134217728);
  u16* Qt   = (u16*)(ws + 201326592);
  u16* H1   = (u16*)(ws + 0);
  // Slot B [256MB, 320MB): Y(ln1) -> Kt -> Y2(ln2), all 64MB, strictly sequential lifetimes.
  u16* Y    = (u16*)(ws + 268435456);
  u16* Kt   = (u16*)(ws + 268435456);
  float* S    = (float*)(ws + 335544320);   // B*H*4096 complex f32 = 4 MB
  float* attn = (float*)(ws + 339738624);   // B*H*4096 f32 = 2 MB
  float* oav  = (float*)(ws + 341835776);   // 32 KB
  float* proj = (float*)(ws + 341868544);   // 32 KB
  u16* Wqb  = (u16*)(ws + 341901312);
  u16* Wkb  = (u16*)(ws + 343998464);
  u16* Wvb  = (u16*)(ws + 346095616);
  u16* W1b  = (u16*)(ws + 348192768);
  u16* W2b  = (u16*)(ws + 356581376);       // ends at ~365 MB

  // weights -> bf16
  k_cvt<<<4096, 256, 0, stream>>>(Wq, Wqb, 1048576);
  k_cvt<<<4096, 256, 0, stream>>>(Wk, Wkb, 1048576);
  k_cvt<<<4096, 256, 0, stream>>>(Wv, Wvb, 1048576);
  k_cvt<<<16384, 256, 0, stream>>>(W1, W1b, 4194304);
  k_cvt<<<16384, 256, 0, stream>>>(W2, W2b, 4194304);

  // y = LN1(x)
  k_ln<<<32768, 256, 0, stream>>>(x, ln1w, ln1b, Y);

  // Q,K,V projections
  k_gemm<0><<<dim3(8, 256), 256, 0, stream>>>(Y, Wqb, bq, Q, 32768, 1024, 1024);
  k_gemm<0><<<dim3(8, 256), 256, 0, stream>>>(Y, Wkb, bk, Kb, 32768, 1024, 1024);
  k_gemm<0><<<dim3(8, 256), 256, 0, stream>>>(Y, Wvb, bv, V, 32768, 1024, 1024);

  // transpose to (B,H,64,L) for contiguous FFT columns
  k_tr<<<dim3(64, 128), 256, 0, stream>>>(Q, Qt);
  k_tr<<<dim3(64, 128), 256, 0, stream>>>(Kb, Kt);

  // S[f] = sum_d rfft(Q_d) * conj(rfft(K_d))   (full Hermitian spectrum)
  hipMemsetAsync(S, 0, 4194304, stream);
  k_fftcorr<<<dim3(128, 4), 256, 0, stream>>>(Qt, Kt, S);
  // corr = ifft(S)/(N*HD); attn = softmax(corr)
  k_isoftmax<<<128, 256, 0, stream>>>(S, attn);
  // out_av[b, hd*16+h] = sum_l attn * V
  k_av<<<128, 256, 0, stream>>>(attn, V, oav);
  // proj = oav @ Wo^T + bo
  k_proj<<<dim3(8, 4), 256, 0, stream>>>(oav, Wo, bo, proj);

  // x2 = (x + proj) - movavg25(x + proj)  -> d_out
  k_decomp<<<dim3(32768, 4), 256, 0, stream>>>(x, proj, out);

  // y2 = LN2(x2)
  k_ln<<<32768, 256, 0, stream>>>(out, ln2w, ln2b, Y);

  // MLP: h1 = gelu(y2 @ W1^T + b1);  d_out = x2 + h1 @ W2^T + b2
  k_gemm<1><<<dim3(32, 256), 256, 0, stream>>>(Y, W1b, b1, H1, 32768, 4096, 1024);
  k_gemm<2><<<dim3(8, 256), 256, 0, stream>>>(H1, W2b, b2, out, 32768, 1024, 4096);
}